// Round 16
// baseline (74.642 us; speedup 1.0000x reference)
//
#include <hip/hip_runtime.h>
#include <hip/hip_bf16.h>

typedef __attribute__((ext_vector_type(4))) float f32x4;
typedef __attribute__((ext_vector_type(8))) short s16x8;
typedef __attribute__((ext_vector_type(2))) __fp16 h16x2;

// inputs: [3136][64][16] f32, W: [10][64][16][16] f32, out: [3136][10][16] f32.
// Gram-space routing per (pos,n): G = R^T R (MFMA bf16), s0 = (1/64) R^T 1,
// s += G*squash(s) x2, out = squash(s).
//
// R16 = R15 with the out-store paren typo fixed. ZERO barriers: each wave
// independently owns one (quad, n) unit; private 8KB LDS slice; einsum
// (verified fdot2, 4 i-segments with per-segment W reload) -> intra-wave
// lgkmcnt -> MFMA Gram -> 4 interleaved routing chains. XCD swizzle kept.

template<int CTRL>
__device__ __forceinline__ float dpp_add(float x) {
    int v = __builtin_amdgcn_update_dpp(0, __float_as_int(x), CTRL, 0xF, 0xF, true);
    return x + __int_as_float(v);
}
template<int CTRL>
__device__ __forceinline__ int dpp_mov(int x) {
    return __builtin_amdgcn_update_dpp(0, x, CTRL, 0xF, 0xF, true);
}
__device__ __forceinline__ h16x2 bch(int x) { return __builtin_bit_cast(h16x2, x); }
__device__ __forceinline__ int bci(h16x2 x) { return __builtin_bit_cast(int, x); }

__global__ __launch_bounds__(256, 4) void caps_kernel(
    const float* __restrict__ inp,
    const float* __restrict__ W,
    float* __restrict__ out)
{
    const int tid = threadIdx.x;
    const int w   = tid >> 6;
    const int l   = tid & 63;

    // XCD swizzle (R14) + per-wave unit: u = widx*4 + w; quad = u/10, n = u%10
    const int bid  = blockIdx.x;
    const int widx = (bid & 7) * 245 + (bid >> 3);   // 0..1959
    const int u    = widx * 4 + w;                   // 0..7839
    const int quad = u / 10;                         // 0..783
    const int n    = u - quad * 10;                  // 0..9

    extern __shared__ __align__(16) char smem[];
    char* rbuf = smem + w * 8192;     // wave-private 8KB: 4 pos x 2KB

    const int i4 = l >> 2;          // row within 16-block
    const int oq = l & 3;           // o-quad / own e-chunk
    const int col = l & 15;
    const int kg  = l >> 4;

    s16x8 ones;
#pragma unroll
    for (int j = 0; j < 8; ++j) ones[j] = (short)0x3F80;  // bf16 1.0

    // ---- einsum: 4 i-segments; segment sg covers i = sg*16 + (l>>2)
#pragma unroll
    for (int sg = 0; sg < 4; ++sg) {
        const int irow = sg * 16 + i4;    // input capsule 0..63

        // W pack for this segment (rotation-ordered, verified layout)
        const float* wb = W + (size_t)n * 16384 + irow * 256 + oq * 4;
        h16x2 wpk[32];
#pragma unroll
        for (int r = 0; r < 4; ++r) {
            int c = (oq + r) & 3;
            f32x4 w0 = *(const f32x4*)(wb + (c * 4 + 0) * 16);
            f32x4 w1 = *(const f32x4*)(wb + (c * 4 + 1) * 16);
            f32x4 w2 = *(const f32x4*)(wb + (c * 4 + 2) * 16);
            f32x4 w3 = *(const f32x4*)(wb + (c * 4 + 3) * 16);
#pragma unroll
            for (int dd = 0; dd < 4; ++dd) {
                wpk[r * 8 + dd]     = __builtin_amdgcn_cvt_pkrtz(w0[dd], w1[dd]);
                wpk[r * 8 + 4 + dd] = __builtin_amdgcn_cvt_pkrtz(w2[dd], w3[dd]);
            }
        }

#pragma unroll
        for (int p = 0; p < 4; ++p) {
            // inp[quad*4+p][irow][oq*4..+3] == base + l*4 floats: coalesced
            f32x4 a = *(const f32x4*)(inp + (size_t)quad * 4096 + p * 1024 + irow * 16 + oq * 4);
            int iA = bci(__builtin_amdgcn_cvt_pkrtz(a[0], a[1]));
            int iB = bci(__builtin_amdgcn_cvt_pkrtz(a[2], a[3]));
            float acc0 = 0.f, acc1 = 0.f, acc2 = 0.f, acc3 = 0.f;

            acc0 = __builtin_amdgcn_fdot2(bch(iA), wpk[0], acc0, false);
            acc1 = __builtin_amdgcn_fdot2(bch(iA), wpk[1], acc1, false);
            acc2 = __builtin_amdgcn_fdot2(bch(iA), wpk[2], acc2, false);
            acc3 = __builtin_amdgcn_fdot2(bch(iA), wpk[3], acc3, false);
            acc0 = __builtin_amdgcn_fdot2(bch(iB), wpk[4], acc0, false);
            acc1 = __builtin_amdgcn_fdot2(bch(iB), wpk[5], acc1, false);
            acc2 = __builtin_amdgcn_fdot2(bch(iB), wpk[6], acc2, false);
            acc3 = __builtin_amdgcn_fdot2(bch(iB), wpk[7], acc3, false);
            {
                int jA = dpp_mov<0x39>(iA), jB = dpp_mov<0x39>(iB);
                acc0 = __builtin_amdgcn_fdot2(bch(jA), wpk[8],  acc0, false);
                acc1 = __builtin_amdgcn_fdot2(bch(jA), wpk[9],  acc1, false);
                acc2 = __builtin_amdgcn_fdot2(bch(jA), wpk[10], acc2, false);
                acc3 = __builtin_amdgcn_fdot2(bch(jA), wpk[11], acc3, false);
                acc0 = __builtin_amdgcn_fdot2(bch(jB), wpk[12], acc0, false);
                acc1 = __builtin_amdgcn_fdot2(bch(jB), wpk[13], acc1, false);
                acc2 = __builtin_amdgcn_fdot2(bch(jB), wpk[14], acc2, false);
                acc3 = __builtin_amdgcn_fdot2(bch(jB), wpk[15], acc3, false);
            }
            {
                int jA = dpp_mov<0x4E>(iA), jB = dpp_mov<0x4E>(iB);
                acc0 = __builtin_amdgcn_fdot2(bch(jA), wpk[16], acc0, false);
                acc1 = __builtin_amdgcn_fdot2(bch(jA), wpk[17], acc1, false);
                acc2 = __builtin_amdgcn_fdot2(bch(jA), wpk[18], acc2, false);
                acc3 = __builtin_amdgcn_fdot2(bch(jA), wpk[19], acc3, false);
                acc0 = __builtin_amdgcn_fdot2(bch(jB), wpk[20], acc0, false);
                acc1 = __builtin_amdgcn_fdot2(bch(jB), wpk[21], acc1, false);
                acc2 = __builtin_amdgcn_fdot2(bch(jB), wpk[22], acc2, false);
                acc3 = __builtin_amdgcn_fdot2(bch(jB), wpk[23], acc3, false);
            }
            {
                int jA = dpp_mov<0x93>(iA), jB = dpp_mov<0x93>(iB);
                acc0 = __builtin_amdgcn_fdot2(bch(jA), wpk[24], acc0, false);
                acc1 = __builtin_amdgcn_fdot2(bch(jA), wpk[25], acc1, false);
                acc2 = __builtin_amdgcn_fdot2(bch(jA), wpk[26], acc2, false);
                acc3 = __builtin_amdgcn_fdot2(bch(jA), wpk[27], acc3, false);
                acc0 = __builtin_amdgcn_fdot2(bch(jB), wpk[28], acc0, false);
                acc1 = __builtin_amdgcn_fdot2(bch(jB), wpk[29], acc1, false);
                acc2 = __builtin_amdgcn_fdot2(bch(jB), wpk[30], acc2, false);
                acc3 = __builtin_amdgcn_fdot2(bch(jB), wpk[31], acc3, false);
            }

            // bf16 scatter into wave-private [p][o][i] (chunk-XOR swizzle)
            float accv[4] = {acc0, acc1, acc2, acc3};
#pragma unroll
            for (int dd = 0; dd < 4; ++dd) {
                int o = oq * 4 + dd;
                __hip_bfloat16 bb = __float2bfloat16(accv[dd]);
                int byte = p * 2048 + o * 128 + (((irow >> 3) ^ (o & 7)) << 4) + (irow & 7) * 2;
                *(unsigned short*)(rbuf + byte) = *(unsigned short*)&bb;
            }
        }
    }

    // intra-wave only: drain LDS writes before fragment reads (NO s_barrier)
    asm volatile("s_waitcnt lgkmcnt(0)" ::: "memory");
    __builtin_amdgcn_sched_barrier(0);

    // ---- phase B: this wave's 4 positions = 4 independent chains
    float s[4];
    f32x4 G[4];
#pragma unroll
    for (int c = 0; c < 4; ++c) {
        s16x8 fr0 = *(const s16x8*)(rbuf + c * 2048 + col * 128 + (((kg + 0) ^ (col & 7)) << 4));
        s16x8 fr1 = *(const s16x8*)(rbuf + c * 2048 + col * 128 + (((kg + 4) ^ (col & 7)) << 4));
        f32x4 g  = (f32x4)0.0f;
        f32x4 c2 = (f32x4)0.0f;
        g  = __builtin_amdgcn_mfma_f32_16x16x32_bf16(fr0, fr0, g, 0, 0, 0);
        g  = __builtin_amdgcn_mfma_f32_16x16x32_bf16(fr1, fr1, g, 0, 0, 0);
        c2 = __builtin_amdgcn_mfma_f32_16x16x32_bf16(ones, fr0, c2, 0, 0, 0);
        c2 = __builtin_amdgcn_mfma_f32_16x16x32_bf16(ones, fr1, c2, 0, 0, 0);
        G[c] = g;
        s[c] = c2[0] * (1.0f / 64.0f);
    }

#pragma unroll
    for (int it = 0; it < 2; ++it) {
#pragma unroll
        for (int c = 0; c < 4; ++c) {
            float sn = s[c] * s[c];
            sn = dpp_add<0xB1>(sn);
            sn = dpp_add<0x4E>(sn);
            sn = dpp_add<0x124>(sn);
            sn = dpp_add<0x128>(sn);
            float scale = sqrtf(sn) / (1.0f + sn);
            float v = scale * s[c];
            float v0 = __shfl(v, kg * 4 + 0);
            float v1 = __shfl(v, kg * 4 + 1);
            float v2 = __shfl(v, kg * 4 + 2);
            float v3 = __shfl(v, kg * 4 + 3);
            float acc = G[c][0] * v0 + G[c][1] * v1 + G[c][2] * v2 + G[c][3] * v3;
            acc += __shfl_xor(acc, 16);
            acc += __shfl_xor(acc, 32);
            s[c] += acc;
        }
    }

#pragma unroll
    for (int c = 0; c < 4; ++c) {
        float sn = s[c] * s[c];
        sn = dpp_add<0xB1>(sn);
        sn = dpp_add<0x4E>(sn);
        sn = dpp_add<0x124>(sn);
        sn = dpp_add<0x128>(sn);
        float scale = sqrtf(sn) / (1.0f + sn);
        float v = scale * s[c];
        if (l < 16)
            out[((size_t)(quad * 4 + c) * 10 + n) * 16 + col] = v;
    }
}

extern "C" void kernel_launch(void* const* d_in, const int* in_sizes, int n_in,
                              void* d_out, int out_size, void* d_ws, size_t ws_size,
                              hipStream_t stream) {
    const float* inp = (const float*)d_in[0];   // [3136][64][16]
    const float* W   = (const float*)d_in[1];   // [10][64][16][16]
    float* out = (float*)d_out;                 // [3136][10][16]

    // 7840 (quad,n) units, 1 per wave, 4 waves/block; 32 KB dyn LDS; no barriers
    dim3 grid(1960), block(256);
    hipLaunchKernelGGL(caps_kernel, grid, block, 32768, stream, inp, W, out);
}

// Round 17
// 43.624 us; speedup vs baseline: 1.7110x; 1.7110x over previous
//
#include <hip/hip_runtime.h>
#include <hip/hip_bf16.h>

typedef __attribute__((ext_vector_type(4))) float f32x4;
typedef __attribute__((ext_vector_type(8))) short s16x8;
typedef __attribute__((ext_vector_type(2))) __fp16 h16x2;

// inputs: [3136][64][16] f32, W: [10][64][16][16] f32, out: [3136][10][16] f32.
// Gram-space routing per (pos,n): G = R^T R (MFMA bf16), s0 = (1/64) R^T 1,
// s += G*squash(s) x2, out = squash(s).
//
// R17 = R14's verified subsystems re-packed for occupancy: block = (n, 2
// quads) one-shot, 8 positions, ONE barrier, 2 routing chains/wave;
// raw in two 4-position batches (peak VGPR ~75); 16KB LDS; launch_bounds
// (256,6) -> target 6 blocks/CU (24 waves). XCD swizzle for grid 3920.

template<int CTRL>
__device__ __forceinline__ float dpp_add(float x) {
    int v = __builtin_amdgcn_update_dpp(0, __float_as_int(x), CTRL, 0xF, 0xF, true);
    return x + __int_as_float(v);
}
template<int CTRL>
__device__ __forceinline__ int dpp_mov(int x) {
    return __builtin_amdgcn_update_dpp(0, x, CTRL, 0xF, 0xF, true);
}
__device__ __forceinline__ h16x2 bch(int x) { return __builtin_bit_cast(h16x2, x); }
__device__ __forceinline__ int bci(h16x2 x) { return __builtin_bit_cast(int, x); }

// verified fdot2 einsum + bf16 scatter for one position PP (uses wpk, oq, i_, rbuf)
#define EINSUM_PP(ARAW, PP)                                                     \
    {                                                                           \
        f32x4 a = (ARAW);                                                       \
        int iA = bci(__builtin_amdgcn_cvt_pkrtz(a[0], a[1]));                   \
        int iB = bci(__builtin_amdgcn_cvt_pkrtz(a[2], a[3]));                   \
        float acc0 = 0.f, acc1 = 0.f, acc2 = 0.f, acc3 = 0.f;                   \
        acc0 = __builtin_amdgcn_fdot2(bch(iA), wpk[0], acc0, false);            \
        acc1 = __builtin_amdgcn_fdot2(bch(iA), wpk[1], acc1, false);            \
        acc2 = __builtin_amdgcn_fdot2(bch(iA), wpk[2], acc2, false);            \
        acc3 = __builtin_amdgcn_fdot2(bch(iA), wpk[3], acc3, false);            \
        acc0 = __builtin_amdgcn_fdot2(bch(iB), wpk[4], acc0, false);            \
        acc1 = __builtin_amdgcn_fdot2(bch(iB), wpk[5], acc1, false);            \
        acc2 = __builtin_amdgcn_fdot2(bch(iB), wpk[6], acc2, false);            \
        acc3 = __builtin_amdgcn_fdot2(bch(iB), wpk[7], acc3, false);            \
        {                                                                       \
            int jA = dpp_mov<0x39>(iA), jB = dpp_mov<0x39>(iB);                 \
            acc0 = __builtin_amdgcn_fdot2(bch(jA), wpk[8],  acc0, false);       \
            acc1 = __builtin_amdgcn_fdot2(bch(jA), wpk[9],  acc1, false);       \
            acc2 = __builtin_amdgcn_fdot2(bch(jA), wpk[10], acc2, false);       \
            acc3 = __builtin_amdgcn_fdot2(bch(jA), wpk[11], acc3, false);       \
            acc0 = __builtin_amdgcn_fdot2(bch(jB), wpk[12], acc0, false);       \
            acc1 = __builtin_amdgcn_fdot2(bch(jB), wpk[13], acc1, false);       \
            acc2 = __builtin_amdgcn_fdot2(bch(jB), wpk[14], acc2, false);       \
            acc3 = __builtin_amdgcn_fdot2(bch(jB), wpk[15], acc3, false);       \
        }                                                                       \
        {                                                                       \
            int jA = dpp_mov<0x4E>(iA), jB = dpp_mov<0x4E>(iB);                 \
            acc0 = __builtin_amdgcn_fdot2(bch(jA), wpk[16], acc0, false);       \
            acc1 = __builtin_amdgcn_fdot2(bch(jA), wpk[17], acc1, false);       \
            acc2 = __builtin_amdgcn_fdot2(bch(jA), wpk[18], acc2, false);       \
            acc3 = __builtin_amdgcn_fdot2(bch(jA), wpk[19], acc3, false);       \
            acc0 = __builtin_amdgcn_fdot2(bch(jB), wpk[20], acc0, false);       \
            acc1 = __builtin_amdgcn_fdot2(bch(jB), wpk[21], acc1, false);       \
            acc2 = __builtin_amdgcn_fdot2(bch(jB), wpk[22], acc2, false);       \
            acc3 = __builtin_amdgcn_fdot2(bch(jB), wpk[23], acc3, false);       \
        }                                                                       \
        {                                                                       \
            int jA = dpp_mov<0x93>(iA), jB = dpp_mov<0x93>(iB);                 \
            acc0 = __builtin_amdgcn_fdot2(bch(jA), wpk[24], acc0, false);       \
            acc1 = __builtin_amdgcn_fdot2(bch(jA), wpk[25], acc1, false);       \
            acc2 = __builtin_amdgcn_fdot2(bch(jA), wpk[26], acc2, false);       \
            acc3 = __builtin_amdgcn_fdot2(bch(jA), wpk[27], acc3, false);       \
            acc0 = __builtin_amdgcn_fdot2(bch(jB), wpk[28], acc0, false);       \
            acc1 = __builtin_amdgcn_fdot2(bch(jB), wpk[29], acc1, false);       \
            acc2 = __builtin_amdgcn_fdot2(bch(jB), wpk[30], acc2, false);       \
            acc3 = __builtin_amdgcn_fdot2(bch(jB), wpk[31], acc3, false);       \
        }                                                                       \
        float accv[4] = {acc0, acc1, acc2, acc3};                               \
        _Pragma("unroll")                                                       \
        for (int dd = 0; dd < 4; ++dd) {                                        \
            int o = oq * 4 + dd;                                                \
            __hip_bfloat16 bb = __float2bfloat16(accv[dd]);                     \
            int byte = (PP) * 2048 + o * 128 +                                  \
                       (((i_ >> 3) ^ (o & 7)) << 4) + (i_ & 7) * 2;             \
            *(unsigned short*)(rbuf + byte) = *(unsigned short*)&bb;            \
        }                                                                       \
    }

__global__ __launch_bounds__(256, 6) void caps_kernel(
    const float* __restrict__ inp,
    const float* __restrict__ W,
    float* __restrict__ out)
{
    const int tid = threadIdx.x;
    const int w   = tid >> 6;
    const int l   = tid & 63;

    // XCD swizzle: 3920 = 8 x 490; widx pg-major so same-pg n-blocks co-locate
    const int bid  = blockIdx.x;
    const int widx = (bid & 7) * 490 + (bid >> 3);   // 0..3919
    const int pg   = widx / 10;                      // 0..391
    const int n    = widx - pg * 10;                 // 0..9
    const int pos0 = pg * 8;                         // 8 positions per block

    extern __shared__ __align__(16) char smem[];
    char* rbuf = smem;                 // 8 pos x 2KB = 16KB

    const int i4 = l >> 2;
    const int oq = l & 3;
    const int i_ = w * 16 + i4;        // input capsule 0..63
    const int col = l & 15;
    const int kg  = l >> 4;

    // ---- W straight to regs, rotation-ordered packed f16 pairs (verified)
    const float* wb = W + (size_t)n * 16384 + i_ * 256 + oq * 4;
    h16x2 wpk[32];
#pragma unroll
    for (int r = 0; r < 4; ++r) {
        int c = (oq + r) & 3;
        f32x4 w0 = *(const f32x4*)(wb + (c * 4 + 0) * 16);
        f32x4 w1 = *(const f32x4*)(wb + (c * 4 + 1) * 16);
        f32x4 w2 = *(const f32x4*)(wb + (c * 4 + 2) * 16);
        f32x4 w3 = *(const f32x4*)(wb + (c * 4 + 3) * 16);
#pragma unroll
        for (int dd = 0; dd < 4; ++dd) {
            wpk[r * 8 + dd]     = __builtin_amdgcn_cvt_pkrtz(w0[dd], w1[dd]);
            wpk[r * 8 + 4 + dd] = __builtin_amdgcn_cvt_pkrtz(w2[dd], w3[dd]);
        }
    }

    s16x8 ones;
#pragma unroll
    for (int j = 0; j < 8; ++j) ones[j] = (short)0x3F80;  // bf16 1.0

    // ---- einsum in two 4-position batches (raw[4] keeps peak VGPR ~75)
    {
        f32x4 raw[4];
#pragma unroll
        for (int j = 0; j < 4; ++j)
            raw[j] = *(const f32x4*)(inp + (size_t)(pos0 + j) * 1024 + w * 256 + l * 4);
#pragma unroll
        for (int j = 0; j < 4; ++j)
            EINSUM_PP(raw[j], j)
#pragma unroll
        for (int j = 0; j < 4; ++j)
            raw[j] = *(const f32x4*)(inp + (size_t)(pos0 + 4 + j) * 1024 + w * 256 + l * 4);
#pragma unroll
        for (int j = 0; j < 4; ++j)
            EINSUM_PP(raw[j], 4 + j)
    }

    // ---- ONE barrier
    asm volatile("s_waitcnt lgkmcnt(0)" ::: "memory");
    __builtin_amdgcn_s_barrier();
    asm volatile("" ::: "memory");
    __builtin_amdgcn_sched_barrier(0);

    // ---- phase B (verified): wave w handles pp = w and pp = w+4
    float s[2];
    f32x4 G[2];
#pragma unroll
    for (int c = 0; c < 2; ++c) {
        const int pp = w + 4 * c;
        s16x8 fr0 = *(const s16x8*)(rbuf + pp * 2048 + col * 128 + (((kg + 0) ^ (col & 7)) << 4));
        s16x8 fr1 = *(const s16x8*)(rbuf + pp * 2048 + col * 128 + (((kg + 4) ^ (col & 7)) << 4));
        f32x4 g  = (f32x4)0.0f;
        f32x4 c2 = (f32x4)0.0f;
        g  = __builtin_amdgcn_mfma_f32_16x16x32_bf16(fr0, fr0, g, 0, 0, 0);
        g  = __builtin_amdgcn_mfma_f32_16x16x32_bf16(fr1, fr1, g, 0, 0, 0);
        c2 = __builtin_amdgcn_mfma_f32_16x16x32_bf16(ones, fr0, c2, 0, 0, 0);
        c2 = __builtin_amdgcn_mfma_f32_16x16x32_bf16(ones, fr1, c2, 0, 0, 0);
        G[c] = g;
        s[c] = c2[0] * (1.0f / 64.0f);
    }

#pragma unroll
    for (int it = 0; it < 2; ++it) {
#pragma unroll
        for (int c = 0; c < 2; ++c) {
            float sn = s[c] * s[c];
            sn = dpp_add<0xB1>(sn);
            sn = dpp_add<0x4E>(sn);
            sn = dpp_add<0x124>(sn);
            sn = dpp_add<0x128>(sn);
            float scale = sqrtf(sn) / (1.0f + sn);
            float v = scale * s[c];
            float v0 = __shfl(v, kg * 4 + 0);
            float v1 = __shfl(v, kg * 4 + 1);
            float v2 = __shfl(v, kg * 4 + 2);
            float v3 = __shfl(v, kg * 4 + 3);
            float acc = G[c][0] * v0 + G[c][1] * v1 + G[c][2] * v2 + G[c][3] * v3;
            acc += __shfl_xor(acc, 16);
            acc += __shfl_xor(acc, 32);
            s[c] += acc;
        }
    }

#pragma unroll
    for (int c = 0; c < 2; ++c) {
        float sn = s[c] * s[c];
        sn = dpp_add<0xB1>(sn);
        sn = dpp_add<0x4E>(sn);
        sn = dpp_add<0x124>(sn);
        sn = dpp_add<0x128>(sn);
        float scale = sqrtf(sn) / (1.0f + sn);
        float v = scale * s[c];
        if (l < 16)
            out[((size_t)(pos0 + w + 4 * c) * 10 + n) * 16 + col] = v;
    }
}

extern "C" void kernel_launch(void* const* d_in, const int* in_sizes, int n_in,
                              void* d_out, int out_size, void* d_ws, size_t ws_size,
                              hipStream_t stream) {
    const float* inp = (const float*)d_in[0];   // [3136][64][16]
    const float* W   = (const float*)d_in[1];   // [10][64][16][16]
    float* out = (float*)d_out;                 // [3136][10][16]

    // 10 n * 392 groups of 8 positions = 3920 blocks; 16 KB dyn LDS
    dim3 grid(3920), block(256);
    hipLaunchKernelGGL(caps_kernel, grid, block, 16384, stream, inp, W, out);
}

// Round 18
// 34.128 us; speedup vs baseline: 2.1871x; 1.2782x over previous
//
#include <hip/hip_runtime.h>
#include <hip/hip_bf16.h>

typedef __attribute__((ext_vector_type(4))) float f32x4;
typedef __attribute__((ext_vector_type(8))) short s16x8;
typedef __attribute__((ext_vector_type(2))) __fp16 h16x2;

// inputs: [3136][64][16] f32, W: [10][64][16][16] f32, out: [3136][10][16] f32.
// Gram-space routing per (pos,n): G = R^T R (MFMA bf16), s0 = (1/64) R^T 1,
// s += G*squash(s) x2, out = squash(s).
//
// R18 = R13's verified machinery with W amortized over 32 positions/block:
// grid 980 (=98 pg x 10 n) halves the dominant W L2-traffic (500->250MB).
// Two half-iters: einsum 16 pos (two raw[8] batches) -> barrier -> phase B
// (4 chains/wave) -> barrier; single 32KB res buffer; launch_bounds(256,4).

template<int CTRL>
__device__ __forceinline__ float dpp_add(float x) {
    int v = __builtin_amdgcn_update_dpp(0, __float_as_int(x), CTRL, 0xF, 0xF, true);
    return x + __int_as_float(v);
}
template<int CTRL>
__device__ __forceinline__ int dpp_mov(int x) {
    return __builtin_amdgcn_update_dpp(0, x, CTRL, 0xF, 0xF, true);
}
__device__ __forceinline__ h16x2 bch(int x) { return __builtin_bit_cast(h16x2, x); }
__device__ __forceinline__ int bci(h16x2 x) { return __builtin_bit_cast(int, x); }

// verified fdot2 einsum + bf16 scatter for one position PP (uses wpk, oq, i_, rbuf)
#define EINSUM_PP(ARAW, PP)                                                     \
    {                                                                           \
        f32x4 a = (ARAW);                                                       \
        int iA = bci(__builtin_amdgcn_cvt_pkrtz(a[0], a[1]));                   \
        int iB = bci(__builtin_amdgcn_cvt_pkrtz(a[2], a[3]));                   \
        float acc0 = 0.f, acc1 = 0.f, acc2 = 0.f, acc3 = 0.f;                   \
        acc0 = __builtin_amdgcn_fdot2(bch(iA), wpk[0], acc0, false);            \
        acc1 = __builtin_amdgcn_fdot2(bch(iA), wpk[1], acc1, false);            \
        acc2 = __builtin_amdgcn_fdot2(bch(iA), wpk[2], acc2, false);            \
        acc3 = __builtin_amdgcn_fdot2(bch(iA), wpk[3], acc3, false);            \
        acc0 = __builtin_amdgcn_fdot2(bch(iB), wpk[4], acc0, false);            \
        acc1 = __builtin_amdgcn_fdot2(bch(iB), wpk[5], acc1, false);            \
        acc2 = __builtin_amdgcn_fdot2(bch(iB), wpk[6], acc2, false);            \
        acc3 = __builtin_amdgcn_fdot2(bch(iB), wpk[7], acc3, false);            \
        {                                                                       \
            int jA = dpp_mov<0x39>(iA), jB = dpp_mov<0x39>(iB);                 \
            acc0 = __builtin_amdgcn_fdot2(bch(jA), wpk[8],  acc0, false);       \
            acc1 = __builtin_amdgcn_fdot2(bch(jA), wpk[9],  acc1, false);       \
            acc2 = __builtin_amdgcn_fdot2(bch(jA), wpk[10], acc2, false);       \
            acc3 = __builtin_amdgcn_fdot2(bch(jA), wpk[11], acc3, false);       \
            acc0 = __builtin_amdgcn_fdot2(bch(jB), wpk[12], acc0, false);       \
            acc1 = __builtin_amdgcn_fdot2(bch(jB), wpk[13], acc1, false);       \
            acc2 = __builtin_amdgcn_fdot2(bch(jB), wpk[14], acc2, false);       \
            acc3 = __builtin_amdgcn_fdot2(bch(jB), wpk[15], acc3, false);       \
        }                                                                       \
        {                                                                       \
            int jA = dpp_mov<0x4E>(iA), jB = dpp_mov<0x4E>(iB);                 \
            acc0 = __builtin_amdgcn_fdot2(bch(jA), wpk[16], acc0, false);       \
            acc1 = __builtin_amdgcn_fdot2(bch(jA), wpk[17], acc1, false);       \
            acc2 = __builtin_amdgcn_fdot2(bch(jA), wpk[18], acc2, false);       \
            acc3 = __builtin_amdgcn_fdot2(bch(jA), wpk[19], acc3, false);       \
            acc0 = __builtin_amdgcn_fdot2(bch(jB), wpk[20], acc0, false);       \
            acc1 = __builtin_amdgcn_fdot2(bch(jB), wpk[21], acc1, false);       \
            acc2 = __builtin_amdgcn_fdot2(bch(jB), wpk[22], acc2, false);       \
            acc3 = __builtin_amdgcn_fdot2(bch(jB), wpk[23], acc3, false);       \
        }                                                                       \
        {                                                                       \
            int jA = dpp_mov<0x93>(iA), jB = dpp_mov<0x93>(iB);                 \
            acc0 = __builtin_amdgcn_fdot2(bch(jA), wpk[24], acc0, false);       \
            acc1 = __builtin_amdgcn_fdot2(bch(jA), wpk[25], acc1, false);       \
            acc2 = __builtin_amdgcn_fdot2(bch(jA), wpk[26], acc2, false);       \
            acc3 = __builtin_amdgcn_fdot2(bch(jA), wpk[27], acc3, false);       \
            acc0 = __builtin_amdgcn_fdot2(bch(jB), wpk[28], acc0, false);       \
            acc1 = __builtin_amdgcn_fdot2(bch(jB), wpk[29], acc1, false);       \
            acc2 = __builtin_amdgcn_fdot2(bch(jB), wpk[30], acc2, false);       \
            acc3 = __builtin_amdgcn_fdot2(bch(jB), wpk[31], acc3, false);       \
        }                                                                       \
        float accv[4] = {acc0, acc1, acc2, acc3};                               \
        _Pragma("unroll")                                                       \
        for (int dd = 0; dd < 4; ++dd) {                                        \
            int o = oq * 4 + dd;                                                \
            __hip_bfloat16 bb = __float2bfloat16(accv[dd]);                     \
            int byte = (PP) * 2048 + o * 128 +                                  \
                       (((i_ >> 3) ^ (o & 7)) << 4) + (i_ & 7) * 2;             \
            *(unsigned short*)(rbuf + byte) = *(unsigned short*)&bb;            \
        }                                                                       \
    }

__global__ __launch_bounds__(256, 4) void caps_kernel(
    const float* __restrict__ inp,
    const float* __restrict__ W,
    float* __restrict__ out)
{
    const int tid = threadIdx.x;
    const int w   = tid >> 6;
    const int l   = tid & 63;
    const int n   = blockIdx.x % 10;
    const int pg  = blockIdx.x / 10;       // 0..97
    const int pos0 = pg * 32;              // 32 positions per block

    extern __shared__ __align__(16) char smem[];
    char* rbuf = smem;                 // 16 pos x 2KB = 32KB (reused per half)

    const int i4 = l >> 2;
    const int oq = l & 3;
    const int i_ = w * 16 + i4;        // input capsule 0..63
    const int col = l & 15;
    const int kg  = l >> 4;

    // ---- W straight to regs, rotation-ordered packed f16 pairs (verified)
    const float* wb = W + (size_t)n * 16384 + i_ * 256 + oq * 4;
    h16x2 wpk[32];
#pragma unroll
    for (int r = 0; r < 4; ++r) {
        int c = (oq + r) & 3;
        f32x4 w0 = *(const f32x4*)(wb + (c * 4 + 0) * 16);
        f32x4 w1 = *(const f32x4*)(wb + (c * 4 + 1) * 16);
        f32x4 w2 = *(const f32x4*)(wb + (c * 4 + 2) * 16);
        f32x4 w3 = *(const f32x4*)(wb + (c * 4 + 3) * 16);
#pragma unroll
        for (int dd = 0; dd < 4; ++dd) {
            wpk[r * 8 + dd]     = __builtin_amdgcn_cvt_pkrtz(w0[dd], w1[dd]);
            wpk[r * 8 + 4 + dd] = __builtin_amdgcn_cvt_pkrtz(w2[dd], w3[dd]);
        }
    }

    s16x8 ones;
#pragma unroll
    for (int j = 0; j < 8; ++j) ones[j] = (short)0x3F80;  // bf16 1.0

    // bpermute gather byte-index (R13-verified)
    const int pidx = (((l & 48) | (((l & 48) >> 2) + (l & 3))) << 2);

#pragma unroll
    for (int t = 0; t < 2; ++t) {
        const int pb = pos0 + t * 16;      // this half's first position

        // ---- einsum 16 positions in two raw[8] batches (verified macro)
        {
            f32x4 raw[8];
#pragma unroll
            for (int j = 0; j < 8; ++j)
                raw[j] = *(const f32x4*)(inp + (size_t)(pb + j) * 1024 + w * 256 + l * 4);
#pragma unroll
            for (int j = 0; j < 8; ++j)
                EINSUM_PP(raw[j], j)
#pragma unroll
            for (int j = 0; j < 8; ++j)
                raw[j] = *(const f32x4*)(inp + (size_t)(pb + 8 + j) * 1024 + w * 256 + l * 4);
#pragma unroll
            for (int j = 0; j < 8; ++j)
                EINSUM_PP(raw[j], 8 + j)
        }

        // barrier: res writes drained before fragment reads
        asm volatile("s_waitcnt lgkmcnt(0)" ::: "memory");
        __builtin_amdgcn_s_barrier();
        asm volatile("" ::: "memory");
        __builtin_amdgcn_sched_barrier(0);

        // ---- phase B (verified): 4 chains/wave, pp = c*4 + w
        float s[4];
        f32x4 G[4];
#pragma unroll
        for (int c = 0; c < 4; ++c) {
            const int pp = c * 4 + w;
            s16x8 fr0 = *(const s16x8*)(rbuf + pp * 2048 + col * 128 + (((kg + 0) ^ (col & 7)) << 4));
            s16x8 fr1 = *(const s16x8*)(rbuf + pp * 2048 + col * 128 + (((kg + 4) ^ (col & 7)) << 4));
            f32x4 g  = (f32x4)0.0f;
            f32x4 c2 = (f32x4)0.0f;
            g  = __builtin_amdgcn_mfma_f32_16x16x32_bf16(fr0, fr0, g, 0, 0, 0);
            g  = __builtin_amdgcn_mfma_f32_16x16x32_bf16(fr1, fr1, g, 0, 0, 0);
            c2 = __builtin_amdgcn_mfma_f32_16x16x32_bf16(ones, fr0, c2, 0, 0, 0);
            c2 = __builtin_amdgcn_mfma_f32_16x16x32_bf16(ones, fr1, c2, 0, 0, 0);
            G[c] = g;
            s[c] = c2[0] * (1.0f / 64.0f);
        }

#pragma unroll
        for (int it = 0; it < 2; ++it) {
#pragma unroll
            for (int c = 0; c < 4; ++c) {
                float sn = s[c] * s[c];
                sn = dpp_add<0xB1>(sn);
                sn = dpp_add<0x4E>(sn);
                sn = dpp_add<0x124>(sn);
                sn = dpp_add<0x128>(sn);
                float scale = sqrtf(sn) / (1.0f + sn);
                float v = scale * s[c];
                int ivp = __builtin_amdgcn_ds_bpermute(pidx, __float_as_int(v));
                float v0 = __int_as_float(dpp_mov<0x00>(ivp));
                float v1 = __int_as_float(dpp_mov<0x55>(ivp));
                float v2 = __int_as_float(dpp_mov<0xAA>(ivp));
                float v3 = __int_as_float(dpp_mov<0xFF>(ivp));
                float acc = G[c][0] * v0 + G[c][1] * v1 + G[c][2] * v2 + G[c][3] * v3;
                acc += __shfl_xor(acc, 16);
                acc += __shfl_xor(acc, 32);
                s[c] += acc;
            }
        }

#pragma unroll
        for (int c = 0; c < 4; ++c) {
            float sn = s[c] * s[c];
            sn = dpp_add<0xB1>(sn);
            sn = dpp_add<0x4E>(sn);
            sn = dpp_add<0x124>(sn);
            sn = dpp_add<0x128>(sn);
            float scale = sqrtf(sn) / (1.0f + sn);
            float v = scale * s[c];
            if (l < 16)
                out[((size_t)(pb + c * 4 + w) * 10 + n) * 16 + col] = v;
        }

        // barrier before next half's einsum overwrites rbuf
        if (t == 0) {
            __builtin_amdgcn_s_barrier();
            asm volatile("" ::: "memory");
        }
    }
}

extern "C" void kernel_launch(void* const* d_in, const int* in_sizes, int n_in,
                              void* d_out, int out_size, void* d_ws, size_t ws_size,
                              hipStream_t stream) {
    const float* inp = (const float*)d_in[0];   // [3136][64][16]
    const float* W   = (const float*)d_in[1];   // [10][64][16][16]
    float* out = (float*)d_out;                 // [3136][10][16]

    // 98 position-groups x 10 n = 980 blocks; 32 KB dyn LDS
    dim3 grid(980), block(256);
    hipLaunchKernelGGL(caps_kernel, grid, block, 32768, stream, inp, W, out);
}

// Round 19
// 32.166 us; speedup vs baseline: 2.3205x; 1.0610x over previous
//
#include <hip/hip_runtime.h>
#include <hip/hip_bf16.h>

typedef __attribute__((ext_vector_type(4))) float f32x4;
typedef __attribute__((ext_vector_type(8))) short s16x8;
typedef __attribute__((ext_vector_type(2))) __fp16 h16x2;

// inputs: [3136][64][16] f32, W: [10][64][16][16] f32, out: [3136][10][16] f32.
// Gram-space routing per (pos,n): G = R^T R (MFMA bf16), s0 = (1/64) R^T 1,
// s += G*squash(s) x2, out = squash(s).
//
// R19 = R14 (best, 30.7us) with occupancy raised: launch_bounds(256,4)
// (16 waves/CU vs 12) and no explicit raw prefetch (loads at iter top;
// extra resident waves hide the latency; peak VGPR ~90 < 128 cap).

template<int CTRL>
__device__ __forceinline__ float dpp_add(float x) {
    int v = __builtin_amdgcn_update_dpp(0, __float_as_int(x), CTRL, 0xF, 0xF, true);
    return x + __int_as_float(v);
}
template<int CTRL>
__device__ __forceinline__ int dpp_mov(int x) {
    return __builtin_amdgcn_update_dpp(0, x, CTRL, 0xF, 0xF, true);
}
__device__ __forceinline__ h16x2 bch(int x) { return __builtin_bit_cast(h16x2, x); }
__device__ __forceinline__ int bci(h16x2 x) { return __builtin_bit_cast(int, x); }

__global__ __launch_bounds__(256, 4) void caps_kernel(
    const float* __restrict__ inp,
    const float* __restrict__ W,
    float* __restrict__ out)
{
    const int tid = threadIdx.x;
    const int w   = tid >> 6;
    const int l   = tid & 63;

    // XCD-locality swizzle (R14-verified): 1960 = 8 XCDs x 245, pg-major
    const int bid  = blockIdx.x;
    const int widx = (bid & 7) * 245 + (bid >> 3);   // 0..1959
    const int qg   = widx / 10;                      // position group 0..195
    const int n    = widx - qg * 10;                 // capsule 0..9
    const int q0   = qg * 4;                         // 4 quads = 16 positions

    extern __shared__ __align__(16) char smem[];
    char* res_s = smem;                // res double buffer: 2 x 16KB

    const int i4 = l >> 2;          // row within 16-block
    const int oq = l & 3;           // o-quad / own e-chunk
    const int i_ = w * 16 + i4;     // input capsule 0..63
    const int col = l & 15;
    const int kg  = l >> 4;

    // ---- W straight to regs, rotation-ordered, packed f16 pairs (verified)
    const float* wb = W + (size_t)n * 16384 + i_ * 256 + oq * 4;
    h16x2 wpk[32];
#pragma unroll
    for (int r = 0; r < 4; ++r) {
        int c = (oq + r) & 3;
        f32x4 w0 = *(const f32x4*)(wb + (c * 4 + 0) * 16);
        f32x4 w1 = *(const f32x4*)(wb + (c * 4 + 1) * 16);
        f32x4 w2 = *(const f32x4*)(wb + (c * 4 + 2) * 16);
        f32x4 w3 = *(const f32x4*)(wb + (c * 4 + 3) * 16);
#pragma unroll
        for (int dd = 0; dd < 4; ++dd) {
            wpk[r * 8 + dd]     = __builtin_amdgcn_cvt_pkrtz(w0[dd], w1[dd]);
            wpk[r * 8 + 4 + dd] = __builtin_amdgcn_cvt_pkrtz(w2[dd], w3[dd]);
        }
    }

    s16x8 ones;
#pragma unroll
    for (int j = 0; j < 8; ++j) ones[j] = (short)0x3F80;  // bf16 1.0

#pragma unroll
    for (int t = 0; t < 2; ++t) {
        char* rbuf = res_s + (t & 1) * 16384;
        const int qb = q0 + 2 * t;          // first quad of this double-quad

        // inp loads at iter top (no explicit prefetch; TLP covers latency)
        f32x4 raw[8];
#pragma unroll
        for (int pp = 0; pp < 8; ++pp)
            raw[pp] = *(const f32x4*)(inp + (size_t)qb * 4096 + pp * 1024 + w * 256 + l * 4);

        // ---- einsum (fdot2, verified): res[pp][i_][oq*4+dd] = sum_e inp*W
#pragma unroll
        for (int pp = 0; pp < 8; ++pp) {
            f32x4 a = raw[pp];
            int iA = bci(__builtin_amdgcn_cvt_pkrtz(a[0], a[1]));
            int iB = bci(__builtin_amdgcn_cvt_pkrtz(a[2], a[3]));
            float acc0 = 0.f, acc1 = 0.f, acc2 = 0.f, acc3 = 0.f;

            acc0 = __builtin_amdgcn_fdot2(bch(iA), wpk[0], acc0, false);
            acc1 = __builtin_amdgcn_fdot2(bch(iA), wpk[1], acc1, false);
            acc2 = __builtin_amdgcn_fdot2(bch(iA), wpk[2], acc2, false);
            acc3 = __builtin_amdgcn_fdot2(bch(iA), wpk[3], acc3, false);
            acc0 = __builtin_amdgcn_fdot2(bch(iB), wpk[4], acc0, false);
            acc1 = __builtin_amdgcn_fdot2(bch(iB), wpk[5], acc1, false);
            acc2 = __builtin_amdgcn_fdot2(bch(iB), wpk[6], acc2, false);
            acc3 = __builtin_amdgcn_fdot2(bch(iB), wpk[7], acc3, false);
            {
                int jA = dpp_mov<0x39>(iA), jB = dpp_mov<0x39>(iB);
                acc0 = __builtin_amdgcn_fdot2(bch(jA), wpk[8],  acc0, false);
                acc1 = __builtin_amdgcn_fdot2(bch(jA), wpk[9],  acc1, false);
                acc2 = __builtin_amdgcn_fdot2(bch(jA), wpk[10], acc2, false);
                acc3 = __builtin_amdgcn_fdot2(bch(jA), wpk[11], acc3, false);
                acc0 = __builtin_amdgcn_fdot2(bch(jB), wpk[12], acc0, false);
                acc1 = __builtin_amdgcn_fdot2(bch(jB), wpk[13], acc1, false);
                acc2 = __builtin_amdgcn_fdot2(bch(jB), wpk[14], acc2, false);
                acc3 = __builtin_amdgcn_fdot2(bch(jB), wpk[15], acc3, false);
            }
            {
                int jA = dpp_mov<0x4E>(iA), jB = dpp_mov<0x4E>(iB);
                acc0 = __builtin_amdgcn_fdot2(bch(jA), wpk[16], acc0, false);
                acc1 = __builtin_amdgcn_fdot2(bch(jA), wpk[17], acc1, false);
                acc2 = __builtin_amdgcn_fdot2(bch(jA), wpk[18], acc2, false);
                acc3 = __builtin_amdgcn_fdot2(bch(jA), wpk[19], acc3, false);
                acc0 = __builtin_amdgcn_fdot2(bch(jB), wpk[20], acc0, false);
                acc1 = __builtin_amdgcn_fdot2(bch(jB), wpk[21], acc1, false);
                acc2 = __builtin_amdgcn_fdot2(bch(jB), wpk[22], acc2, false);
                acc3 = __builtin_amdgcn_fdot2(bch(jB), wpk[23], acc3, false);
            }
            {
                int jA = dpp_mov<0x93>(iA), jB = dpp_mov<0x93>(iB);
                acc0 = __builtin_amdgcn_fdot2(bch(jA), wpk[24], acc0, false);
                acc1 = __builtin_amdgcn_fdot2(bch(jA), wpk[25], acc1, false);
                acc2 = __builtin_amdgcn_fdot2(bch(jA), wpk[26], acc2, false);
                acc3 = __builtin_amdgcn_fdot2(bch(jA), wpk[27], acc3, false);
                acc0 = __builtin_amdgcn_fdot2(bch(jB), wpk[28], acc0, false);
                acc1 = __builtin_amdgcn_fdot2(bch(jB), wpk[29], acc1, false);
                acc2 = __builtin_amdgcn_fdot2(bch(jB), wpk[30], acc2, false);
                acc3 = __builtin_amdgcn_fdot2(bch(jB), wpk[31], acc3, false);
            }

            float accv[4] = {acc0, acc1, acc2, acc3};
#pragma unroll
            for (int dd = 0; dd < 4; ++dd) {
                int o = oq * 4 + dd;
                __hip_bfloat16 bb = __float2bfloat16(accv[dd]);
                int byte = pp * 2048 + o * 128 + (((i_ >> 3) ^ (o & 7)) << 4) + (i_ & 7) * 2;
                *(unsigned short*)(rbuf + byte) = *(unsigned short*)&bb;
            }
        }

        // one barrier per double-quad (res double-buffered)
        asm volatile("s_waitcnt lgkmcnt(0)" ::: "memory");
        __builtin_amdgcn_s_barrier();
        asm volatile("" ::: "memory");
        __builtin_amdgcn_sched_barrier(0);

        // ---- phase B (verified): wave w handles pp = w and pp = w+4
        float s[2];
        f32x4 G[2];
#pragma unroll
        for (int c = 0; c < 2; ++c) {
            const int pp = w + 4 * c;
            s16x8 fr0 = *(const s16x8*)(rbuf + pp * 2048 + col * 128 + (((kg + 0) ^ (col & 7)) << 4));
            s16x8 fr1 = *(const s16x8*)(rbuf + pp * 2048 + col * 128 + (((kg + 4) ^ (col & 7)) << 4));
            f32x4 g  = (f32x4)0.0f;
            f32x4 c2 = (f32x4)0.0f;
            g  = __builtin_amdgcn_mfma_f32_16x16x32_bf16(fr0, fr0, g, 0, 0, 0);
            g  = __builtin_amdgcn_mfma_f32_16x16x32_bf16(fr1, fr1, g, 0, 0, 0);
            c2 = __builtin_amdgcn_mfma_f32_16x16x32_bf16(ones, fr0, c2, 0, 0, 0);
            c2 = __builtin_amdgcn_mfma_f32_16x16x32_bf16(ones, fr1, c2, 0, 0, 0);
            G[c] = g;
            s[c] = c2[0] * (1.0f / 64.0f);
        }

#pragma unroll
        for (int it = 0; it < 2; ++it) {
#pragma unroll
            for (int c = 0; c < 2; ++c) {
                float sn = s[c] * s[c];
                sn = dpp_add<0xB1>(sn);
                sn = dpp_add<0x4E>(sn);
                sn = dpp_add<0x124>(sn);
                sn = dpp_add<0x128>(sn);
                float scale = sqrtf(sn) / (1.0f + sn);
                float v = scale * s[c];
                float v0 = __shfl(v, kg * 4 + 0);
                float v1 = __shfl(v, kg * 4 + 1);
                float v2 = __shfl(v, kg * 4 + 2);
                float v3 = __shfl(v, kg * 4 + 3);
                float acc = G[c][0] * v0 + G[c][1] * v1 + G[c][2] * v2 + G[c][3] * v3;
                acc += __shfl_xor(acc, 16);
                acc += __shfl_xor(acc, 32);
                s[c] += acc;
            }
        }

#pragma unroll
        for (int c = 0; c < 2; ++c) {
            float sn = s[c] * s[c];
            sn = dpp_add<0xB1>(sn);
            sn = dpp_add<0x4E>(sn);
            sn = dpp_add<0x124>(sn);
            sn = dpp_add<0x128>(sn);
            float scale = sqrtf(sn) / (1.0f + sn);
            float v = scale * s[c];
            if (l < 16)
                out[((size_t)((qb + c) * 4 + w) * 10 + n) * 16 + col] = v;
        }
    }
}

extern "C" void kernel_launch(void* const* d_in, const int* in_sizes, int n_in,
                              void* d_out, int out_size, void* d_ws, size_t ws_size,
                              hipStream_t stream) {
    const float* inp = (const float*)d_in[0];   // [3136][64][16]
    const float* W   = (const float*)d_in[1];   // [10][64][16][16]
    float* out = (float*)d_out;                 // [3136][10][16]

    // 10 n * 196 groups of 4 quads; XCD swizzle in kernel; 32 KB dyn LDS
    dim3 grid(1960), block(256);
    hipLaunchKernelGGL(caps_kernel, grid, block, 32768, stream, inp, W, out);
}

// Round 20
// 30.740 us; speedup vs baseline: 2.4282x; 1.0464x over previous
//
#include <hip/hip_runtime.h>
#include <hip/hip_bf16.h>

typedef __attribute__((ext_vector_type(4))) float f32x4;
typedef __attribute__((ext_vector_type(8))) short s16x8;
typedef __attribute__((ext_vector_type(2))) __fp16 h16x2;

// inputs: [3136][64][16] f32, W: [10][64][16][16] f32, out: [3136][10][16] f32.
// Gram-space routing per (pos,n): G = R^T R (MFMA bf16), s0 = (1/64) R^T 1,
// s += G*squash(s) x2, out = squash(s).
//
// R20 = R14 (best, 30.7us) byte-identical EXCEPT launch_bounds(256,3->4):
// clean A/B on occupancy with the prefetch intact (R19 confounded the two).

template<int CTRL>
__device__ __forceinline__ float dpp_add(float x) {
    int v = __builtin_amdgcn_update_dpp(0, __float_as_int(x), CTRL, 0xF, 0xF, true);
    return x + __int_as_float(v);
}
template<int CTRL>
__device__ __forceinline__ int dpp_mov(int x) {
    return __builtin_amdgcn_update_dpp(0, x, CTRL, 0xF, 0xF, true);
}
__device__ __forceinline__ h16x2 bch(int x) { return __builtin_bit_cast(h16x2, x); }
__device__ __forceinline__ int bci(h16x2 x) { return __builtin_bit_cast(int, x); }

__global__ __launch_bounds__(256, 4) void caps_kernel(
    const float* __restrict__ inp,
    const float* __restrict__ W,
    float* __restrict__ out)
{
    const int tid = threadIdx.x;
    const int w   = tid >> 6;
    const int l   = tid & 63;

    // XCD-locality swizzle (R14-verified): 1960 = 8 XCDs x 245, pg-major
    const int bid  = blockIdx.x;
    const int widx = (bid & 7) * 245 + (bid >> 3);   // 0..1959
    const int qg   = widx / 10;                      // position group 0..195
    const int n    = widx - qg * 10;                 // capsule 0..9
    const int q0   = qg * 4;                         // 4 quads = 16 positions

    extern __shared__ __align__(16) char smem[];
    char* res_s = smem;                // res double buffer: 2 x 16KB

    const int i4 = l >> 2;          // row within 16-block
    const int oq = l & 3;           // o-quad / own e-chunk
    const int i_ = w * 16 + i4;     // input capsule 0..63
    const int col = l & 15;
    const int kg  = l >> 4;

    // ---- W straight to regs, rotation-ordered, packed f16 pairs (verified)
    const float* wb = W + (size_t)n * 16384 + i_ * 256 + oq * 4;
    h16x2 wpk[32];
#pragma unroll
    for (int r = 0; r < 4; ++r) {
        int c = (oq + r) & 3;
        f32x4 w0 = *(const f32x4*)(wb + (c * 4 + 0) * 16);
        f32x4 w1 = *(const f32x4*)(wb + (c * 4 + 1) * 16);
        f32x4 w2 = *(const f32x4*)(wb + (c * 4 + 2) * 16);
        f32x4 w3 = *(const f32x4*)(wb + (c * 4 + 3) * 16);
#pragma unroll
        for (int dd = 0; dd < 4; ++dd) {
            wpk[r * 8 + dd]     = __builtin_amdgcn_cvt_pkrtz(w0[dd], w1[dd]);
            wpk[r * 8 + 4 + dd] = __builtin_amdgcn_cvt_pkrtz(w2[dd], w3[dd]);
        }
    }

    s16x8 ones;
#pragma unroll
    for (int j = 0; j < 8; ++j) ones[j] = (short)0x3F80;  // bf16 1.0

    // ---- first double-quad inp load (coalesced 16B/lane)
    f32x4 raw[8], rawn[8];
#pragma unroll
    for (int pp = 0; pp < 8; ++pp)
        raw[pp] = *(const f32x4*)(inp + (size_t)q0 * 4096 + pp * 1024 + w * 256 + l * 4);

#pragma unroll
    for (int t = 0; t < 2; ++t) {
        char* rbuf = res_s + (t & 1) * 16384;
        const int qb = q0 + 2 * t;          // first quad of this double-quad

        // ---- einsum (fdot2, verified): res[pp][i_][oq*4+dd] = sum_e inp*W
#pragma unroll
        for (int pp = 0; pp < 8; ++pp) {
            f32x4 a = raw[pp];
            int iA = bci(__builtin_amdgcn_cvt_pkrtz(a[0], a[1]));
            int iB = bci(__builtin_amdgcn_cvt_pkrtz(a[2], a[3]));
            float acc0 = 0.f, acc1 = 0.f, acc2 = 0.f, acc3 = 0.f;

            acc0 = __builtin_amdgcn_fdot2(bch(iA), wpk[0], acc0, false);
            acc1 = __builtin_amdgcn_fdot2(bch(iA), wpk[1], acc1, false);
            acc2 = __builtin_amdgcn_fdot2(bch(iA), wpk[2], acc2, false);
            acc3 = __builtin_amdgcn_fdot2(bch(iA), wpk[3], acc3, false);
            acc0 = __builtin_amdgcn_fdot2(bch(iB), wpk[4], acc0, false);
            acc1 = __builtin_amdgcn_fdot2(bch(iB), wpk[5], acc1, false);
            acc2 = __builtin_amdgcn_fdot2(bch(iB), wpk[6], acc2, false);
            acc3 = __builtin_amdgcn_fdot2(bch(iB), wpk[7], acc3, false);
            {
                int jA = dpp_mov<0x39>(iA), jB = dpp_mov<0x39>(iB);
                acc0 = __builtin_amdgcn_fdot2(bch(jA), wpk[8],  acc0, false);
                acc1 = __builtin_amdgcn_fdot2(bch(jA), wpk[9],  acc1, false);
                acc2 = __builtin_amdgcn_fdot2(bch(jA), wpk[10], acc2, false);
                acc3 = __builtin_amdgcn_fdot2(bch(jA), wpk[11], acc3, false);
                acc0 = __builtin_amdgcn_fdot2(bch(jB), wpk[12], acc0, false);
                acc1 = __builtin_amdgcn_fdot2(bch(jB), wpk[13], acc1, false);
                acc2 = __builtin_amdgcn_fdot2(bch(jB), wpk[14], acc2, false);
                acc3 = __builtin_amdgcn_fdot2(bch(jB), wpk[15], acc3, false);
            }
            {
                int jA = dpp_mov<0x4E>(iA), jB = dpp_mov<0x4E>(iB);
                acc0 = __builtin_amdgcn_fdot2(bch(jA), wpk[16], acc0, false);
                acc1 = __builtin_amdgcn_fdot2(bch(jA), wpk[17], acc1, false);
                acc2 = __builtin_amdgcn_fdot2(bch(jA), wpk[18], acc2, false);
                acc3 = __builtin_amdgcn_fdot2(bch(jA), wpk[19], acc3, false);
                acc0 = __builtin_amdgcn_fdot2(bch(jB), wpk[20], acc0, false);
                acc1 = __builtin_amdgcn_fdot2(bch(jB), wpk[21], acc1, false);
                acc2 = __builtin_amdgcn_fdot2(bch(jB), wpk[22], acc2, false);
                acc3 = __builtin_amdgcn_fdot2(bch(jB), wpk[23], acc3, false);
            }
            {
                int jA = dpp_mov<0x93>(iA), jB = dpp_mov<0x93>(iB);
                acc0 = __builtin_amdgcn_fdot2(bch(jA), wpk[24], acc0, false);
                acc1 = __builtin_amdgcn_fdot2(bch(jA), wpk[25], acc1, false);
                acc2 = __builtin_amdgcn_fdot2(bch(jA), wpk[26], acc2, false);
                acc3 = __builtin_amdgcn_fdot2(bch(jA), wpk[27], acc3, false);
                acc0 = __builtin_amdgcn_fdot2(bch(jB), wpk[28], acc0, false);
                acc1 = __builtin_amdgcn_fdot2(bch(jB), wpk[29], acc1, false);
                acc2 = __builtin_amdgcn_fdot2(bch(jB), wpk[30], acc2, false);
                acc3 = __builtin_amdgcn_fdot2(bch(jB), wpk[31], acc3, false);
            }

            float accv[4] = {acc0, acc1, acc2, acc3};
#pragma unroll
            for (int dd = 0; dd < 4; ++dd) {
                int o = oq * 4 + dd;
                __hip_bfloat16 bb = __float2bfloat16(accv[dd]);
                int byte = pp * 2048 + o * 128 + (((i_ >> 3) ^ (o & 7)) << 4) + (i_ & 7) * 2;
                *(unsigned short*)(rbuf + byte) = *(unsigned short*)&bb;
            }
        }

        // issue next double-quad loads now; they complete under phase B
        if (t == 0) {
#pragma unroll
            for (int pp = 0; pp < 8; ++pp)
                rawn[pp] = *(const f32x4*)(inp + (size_t)(q0 + 2) * 4096 + pp * 1024 + w * 256 + l * 4);
        }

        // one barrier per double-quad (res double-buffered)
        asm volatile("s_waitcnt lgkmcnt(0)" ::: "memory");
        __builtin_amdgcn_s_barrier();
        asm volatile("" ::: "memory");
        __builtin_amdgcn_sched_barrier(0);

        // ---- phase B (verified): wave w handles pp = w and pp = w+4
        float s[2];
        f32x4 G[2];
#pragma unroll
        for (int c = 0; c < 2; ++c) {
            const int pp = w + 4 * c;
            s16x8 fr0 = *(const s16x8*)(rbuf + pp * 2048 + col * 128 + (((kg + 0) ^ (col & 7)) << 4));
            s16x8 fr1 = *(const s16x8*)(rbuf + pp * 2048 + col * 128 + (((kg + 4) ^ (col & 7)) << 4));
            f32x4 g  = (f32x4)0.0f;
            f32x4 c2 = (f32x4)0.0f;
            g  = __builtin_amdgcn_mfma_f32_16x16x32_bf16(fr0, fr0, g, 0, 0, 0);
            g  = __builtin_amdgcn_mfma_f32_16x16x32_bf16(fr1, fr1, g, 0, 0, 0);
            c2 = __builtin_amdgcn_mfma_f32_16x16x32_bf16(ones, fr0, c2, 0, 0, 0);
            c2 = __builtin_amdgcn_mfma_f32_16x16x32_bf16(ones, fr1, c2, 0, 0, 0);
            G[c] = g;
            s[c] = c2[0] * (1.0f / 64.0f);
        }

#pragma unroll
        for (int it = 0; it < 2; ++it) {
#pragma unroll
            for (int c = 0; c < 2; ++c) {
                float sn = s[c] * s[c];
                sn = dpp_add<0xB1>(sn);
                sn = dpp_add<0x4E>(sn);
                sn = dpp_add<0x124>(sn);
                sn = dpp_add<0x128>(sn);
                float scale = sqrtf(sn) / (1.0f + sn);
                float v = scale * s[c];
                float v0 = __shfl(v, kg * 4 + 0);
                float v1 = __shfl(v, kg * 4 + 1);
                float v2 = __shfl(v, kg * 4 + 2);
                float v3 = __shfl(v, kg * 4 + 3);
                float acc = G[c][0] * v0 + G[c][1] * v1 + G[c][2] * v2 + G[c][3] * v3;
                acc += __shfl_xor(acc, 16);
                acc += __shfl_xor(acc, 32);
                s[c] += acc;
            }
        }

#pragma unroll
        for (int c = 0; c < 2; ++c) {
            float sn = s[c] * s[c];
            sn = dpp_add<0xB1>(sn);
            sn = dpp_add<0x4E>(sn);
            sn = dpp_add<0x124>(sn);
            sn = dpp_add<0x128>(sn);
            float scale = sqrtf(sn) / (1.0f + sn);
            float v = scale * s[c];
            if (l < 16)
                out[((size_t)((qb + c) * 4 + w) * 10 + n) * 16 + col] = v;
        }

        if (t == 0) {
#pragma unroll
            for (int pp = 0; pp < 8; ++pp) raw[pp] = rawn[pp];
        }
    }
}

extern "C" void kernel_launch(void* const* d_in, const int* in_sizes, int n_in,
                              void* d_out, int out_size, void* d_ws, size_t ws_size,
                              hipStream_t stream) {
    const float* inp = (const float*)d_in[0];   // [3136][64][16]
    const float* W   = (const float*)d_in[1];   // [10][64][16][16]
    float* out = (float*)d_out;                 // [3136][10][16]

    // 10 n * 196 groups of 4 quads; XCD swizzle in kernel; 32 KB dyn LDS
    dim3 grid(1960), block(256);
    hipLaunchKernelGGL(caps_kernel, grid, block, 32768, stream, inp, W, out);
}